// Round 2
// baseline (1691.706 us; speedup 1.0000x reference)
//
#include <hip/hip_runtime.h>
#include <math.h>

typedef unsigned short u16;
typedef __attribute__((ext_vector_type(8))) short short8;
typedef __attribute__((ext_vector_type(4))) float floatx4;

__device__ __forceinline__ float bf2f(u16 u) {
  union { unsigned int i; float f; } v; v.i = ((unsigned int)u) << 16; return v.f;
}
__device__ __forceinline__ u16 f2bf(float f) {
  union { unsigned int i; float f; } v; v.f = f;
  unsigned int i = v.i;
  unsigned int lsb = (i >> 16) & 1u;
  i += 0x7fffu + lsb;          // round-to-nearest-even
  return (u16)(i >> 16);
}

// ---------------------------------------------------------------------------
// Generic bf16 MFMA GEMM: C[M x N] = act(A[M x K] @ B[N x K]^T + bias)
// Tiles: 128x128 per block, BK=32, 4 waves in 2x2, each wave 64x64 (4x4 mfma).
// Used for the adj path (link MLP) where bf16 precision passed validation.
// ---------------------------------------------------------------------------
template<bool A_F32, bool OUT_BF16, bool RELU, bool ADJ_EP>
__global__ __launch_bounds__(256, 2)
void gemm_k(const void* __restrict__ Ap, const u16* __restrict__ Bw,
            const float* __restrict__ bias, void* __restrict__ Cp,
            float* __restrict__ adjp, const float* __restrict__ wl3v,
            int N, int K_loop, int K_src, int lda, int ldc)
{
  __shared__ __align__(16) u16 As[128 * 40];   // stride 40 kills bank conflicts
  __shared__ __align__(16) u16 Bs[128 * 40];
  const int tid  = threadIdx.x;
  const int m0   = blockIdx.x * 128;
  const int n0   = blockIdx.y * 128;
  const int lane = tid & 63;
  const int wv   = tid >> 6;
  const int wm   = wv & 1;
  const int wn   = wv >> 1;
  const int q    = lane >> 4;
  const int cl   = lane & 15;

  floatx4 acc[4][4];
#pragma unroll
  for (int i = 0; i < 4; ++i)
#pragma unroll
    for (int j = 0; j < 4; ++j)
      acc[i][j] = (floatx4){0.f, 0.f, 0.f, 0.f};

  const int srow = tid >> 1;          // 0..127
  const int scol = (tid & 1) * 16;    // 0 or 16

  for (int kb = 0; kb < K_loop; kb += 32) {
    {
      const long r = (long)(m0 + srow);
      u16* dst = &As[srow * 40 + scol];
      if (A_F32) {
        const float* A = (const float*)Ap;
#pragma unroll
        for (int j = 0; j < 16; ++j) {
          int kg = kb + scol + j;
          float v = (kg < K_src) ? A[r * lda + kg] : 0.f;
          dst[j] = f2bf(v);
        }
      } else {
        const u16* A = (const u16*)Ap;
        const short8* s = (const short8*)(A + r * lda + kb + scol);
        ((short8*)dst)[0] = s[0];
        ((short8*)dst)[1] = s[1];
      }
    }
    {
      const int n = n0 + srow;
      u16* dst = &Bs[srow * 40 + scol];
      if (n < N) {
        const short8* s = (const short8*)(Bw + (long)n * K_loop + kb + scol);
        ((short8*)dst)[0] = s[0];
        ((short8*)dst)[1] = s[1];
      } else {
#pragma unroll
        for (int j = 0; j < 16; ++j) dst[j] = 0;
      }
    }
    __syncthreads();

    short8 af[4], bfr[4];
#pragma unroll
    for (int mi = 0; mi < 4; ++mi)
      af[mi] = *(const short8*)&As[(wm * 64 + mi * 16 + cl) * 40 + q * 8];
#pragma unroll
    for (int ni = 0; ni < 4; ++ni)
      bfr[ni] = *(const short8*)&Bs[(wn * 64 + ni * 16 + cl) * 40 + q * 8];
#pragma unroll
    for (int mi = 0; mi < 4; ++mi)
#pragma unroll
      for (int ni = 0; ni < 4; ++ni)
        acc[mi][ni] = __builtin_amdgcn_mfma_f32_16x16x32_bf16(af[mi], bfr[ni], acc[mi][ni], 0, 0, 0);
    __syncthreads();
  }

  if (!ADJ_EP) {
#pragma unroll
    for (int mi = 0; mi < 4; ++mi) {
      const int row = m0 + wm * 64 + mi * 16 + q * 4;
#pragma unroll
      for (int ni = 0; ni < 4; ++ni) {
        const int col = n0 + wn * 64 + ni * 16 + cl;
        if (col < N) {
          const float b = bias ? bias[col] : 0.f;
#pragma unroll
          for (int r = 0; r < 4; ++r) {
            float v = acc[mi][ni][r] + b;
            if (RELU) v = fmaxf(v, 0.f);
            const long off = (long)(row + r) * ldc + col;
            if (OUT_BF16) ((u16*)Cp)[off] = f2bf(v);
            else          ((float*)Cp)[off] = v;
          }
        }
      }
    }
  } else {
    // x2 = relu(acc + bias); adj[row] += sum_col x2[row,col] * wl3[col]
#pragma unroll
    for (int mi = 0; mi < 4; ++mi) {
#pragma unroll
      for (int r = 0; r < 4; ++r) {
        float p = 0.f;
#pragma unroll
        for (int ni = 0; ni < 4; ++ni) {
          const int col = n0 + wn * 64 + ni * 16 + cl;
          float v = acc[mi][ni][r] + bias[col];
          v = fmaxf(v, 0.f);
          p += v * wl3v[col];
        }
#pragma unroll
        for (int off = 1; off < 16; off <<= 1)
          p += __shfl_xor(p, off, 64);
        if (cl == 0) {
          const int row = m0 + wm * 64 + mi * 16 + q * 4 + r;
          atomicAdd(&adjp[row], p);
        }
      }
    }
  }
}

// ---------------------------------------------------------------------------
// Split-precision MFMA GEMM (~fp32 accuracy): A fp32 staged as hi+lo bf16,
// B pre-split into hi/lo bf16 buffers; acc = Ah*Bh + Al*Bh + Ah*Bl.
// Per-product rel err ~2^-15 (missing lo*lo only). Used for the whole h path.
// ---------------------------------------------------------------------------
template<bool OUT_BF16>
__global__ __launch_bounds__(256, 2)
void gemm_sp_k(const float* __restrict__ A, const u16* __restrict__ Bh,
               const u16* __restrict__ Bl, const float* __restrict__ bias,
               void* __restrict__ Cp,
               int N, int K_loop, int K_src, int lda, int ldc)
{
  __shared__ __align__(16) u16 Ash[128 * 40];
  __shared__ __align__(16) u16 Asl[128 * 40];
  __shared__ __align__(16) u16 Bsh[128 * 40];
  __shared__ __align__(16) u16 Bsl[128 * 40];
  const int tid  = threadIdx.x;
  const int m0   = blockIdx.x * 128;
  const int n0   = blockIdx.y * 128;
  const int lane = tid & 63;
  const int wv   = tid >> 6;
  const int wm   = wv & 1;
  const int wn   = wv >> 1;
  const int q    = lane >> 4;
  const int cl   = lane & 15;

  floatx4 acc[4][4];
#pragma unroll
  for (int i = 0; i < 4; ++i)
#pragma unroll
    for (int j = 0; j < 4; ++j)
      acc[i][j] = (floatx4){0.f, 0.f, 0.f, 0.f};

  const int srow = tid >> 1;
  const int scol = (tid & 1) * 16;

  for (int kb = 0; kb < K_loop; kb += 32) {
    {
      const long r = (long)(m0 + srow);
      u16* dh = &Ash[srow * 40 + scol];
      u16* dl = &Asl[srow * 40 + scol];
#pragma unroll
      for (int j = 0; j < 16; ++j) {
        int kg = kb + scol + j;
        float v = (kg < K_src) ? A[r * lda + kg] : 0.f;
        u16 hi = f2bf(v);
        dh[j] = hi;
        dl[j] = f2bf(v - bf2f(hi));
      }
    }
    {
      const int n = n0 + srow;
      u16* dh = &Bsh[srow * 40 + scol];
      u16* dl = &Bsl[srow * 40 + scol];
      if (n < N) {
        const short8* sh = (const short8*)(Bh + (long)n * K_loop + kb + scol);
        const short8* sl = (const short8*)(Bl + (long)n * K_loop + kb + scol);
        ((short8*)dh)[0] = sh[0]; ((short8*)dh)[1] = sh[1];
        ((short8*)dl)[0] = sl[0]; ((short8*)dl)[1] = sl[1];
      } else {
#pragma unroll
        for (int j = 0; j < 16; ++j) { dh[j] = 0; dl[j] = 0; }
      }
    }
    __syncthreads();

    short8 ah[4], al[4], bh[4], bl[4];
#pragma unroll
    for (int mi = 0; mi < 4; ++mi) {
      ah[mi] = *(const short8*)&Ash[(wm * 64 + mi * 16 + cl) * 40 + q * 8];
      al[mi] = *(const short8*)&Asl[(wm * 64 + mi * 16 + cl) * 40 + q * 8];
    }
#pragma unroll
    for (int ni = 0; ni < 4; ++ni) {
      bh[ni] = *(const short8*)&Bsh[(wn * 64 + ni * 16 + cl) * 40 + q * 8];
      bl[ni] = *(const short8*)&Bsl[(wn * 64 + ni * 16 + cl) * 40 + q * 8];
    }
#pragma unroll
    for (int mi = 0; mi < 4; ++mi)
#pragma unroll
      for (int ni = 0; ni < 4; ++ni) {
        acc[mi][ni] = __builtin_amdgcn_mfma_f32_16x16x32_bf16(ah[mi], bh[ni], acc[mi][ni], 0, 0, 0);
        acc[mi][ni] = __builtin_amdgcn_mfma_f32_16x16x32_bf16(al[mi], bh[ni], acc[mi][ni], 0, 0, 0);
        acc[mi][ni] = __builtin_amdgcn_mfma_f32_16x16x32_bf16(ah[mi], bl[ni], acc[mi][ni], 0, 0, 0);
      }
    __syncthreads();
  }

#pragma unroll
  for (int mi = 0; mi < 4; ++mi) {
    const int row = m0 + wm * 64 + mi * 16 + q * 4;
#pragma unroll
    for (int ni = 0; ni < 4; ++ni) {
      const int col = n0 + wn * 64 + ni * 16 + cl;
      if (col < N) {
        const float b = bias ? bias[col] : 0.f;
#pragma unroll
        for (int r = 0; r < 4; ++r) {
          float v = acc[mi][ni][r] + b;
          const long off = (long)(row + r) * ldc + col;
          if (OUT_BF16) ((u16*)Cp)[off] = f2bf(v);
          else          ((float*)Cp)[off] = v;
        }
      }
    }
  }
}

// fp32 -> bf16 cast with zero-pad (single buffer, for the bf16-only path)
__global__ void cast_pad_k(u16* __restrict__ dst, const float* __restrict__ src,
                           int rows, int src_cols, int dst_cols, int src_stride,
                           int col_off)
{
  int idx = blockIdx.x * blockDim.x + threadIdx.x;
  int total = rows * dst_cols;
  if (idx >= total) return;
  int r = idx / dst_cols, c = idx - r * dst_cols;
  float v = (c < src_cols) ? src[r * src_stride + col_off + c] : 0.f;
  dst[idx] = f2bf(v);
}

// fp32 -> (hi, lo) bf16 split with zero-pad
__global__ void cast_split_k(u16* __restrict__ dh, u16* __restrict__ dl,
                             const float* __restrict__ src,
                             int rows, int src_cols, int dst_cols, int src_stride,
                             int col_off)
{
  int idx = blockIdx.x * blockDim.x + threadIdx.x;
  int total = rows * dst_cols;
  if (idx >= total) return;
  int r = idx / dst_cols, c = idx - r * dst_cols;
  float v = (c < src_cols) ? src[r * src_stride + col_off + c] : 0.f;
  u16 hi = f2bf(v);
  dh[idx] = hi;
  dl[idx] = f2bf(v - bf2f(hi));
}

// Wcf = W_me @ W_er (fp32, [256 x 224] zero-padded); c_m = W_me @ b_er + b_m
__global__ void wc_k(float* __restrict__ Wcf, float* __restrict__ cm,
                     const float* __restrict__ W_m, const float* __restrict__ W_er,
                     const float* __restrict__ b_er, const float* __restrict__ b_m)
{
  int o = blockIdx.x;        // 0..255  output channel
  int t = threadIdx.x;       // 0..255
  __shared__ float wme[256];
  wme[t] = W_m[o * 512 + 256 + t];
  __syncthreads();
  if (t < 224) {
    float s = 0.f;
    if (t < 200) {
      for (int c = 0; c < 256; ++c) s += wme[c] * W_er[c * 200 + t];
    }
    Wcf[o * 224 + t] = s;
  }
  if (t == 0) {
    float s = 0.f;
    for (int c = 0; c < 256; ++c) s += wme[c] * b_er[c];
    cm[o] = s + b_m[o];
  }
}

__global__ void fill_k(float* __restrict__ p, const float* __restrict__ v, int n)
{
  int i = blockIdx.x * blockDim.x + threadIdx.x;
  if (i < n) p[i] = v[0];
}

// Per-edge message + transpose-scatter + per-target aggregation.
// M[b,i,w,:] = sigmoid(adj[b,i,w]) * relu(Hm[b,w,:] + Em[b,i,w,:])
// es[b,w,i,:] = bf16(M); msum[b,i,:] = sum_w M  (fp32)
__global__ __launch_bounds__(256)
void message_k(const u16* __restrict__ Em, const float* __restrict__ Hm,
               const float* __restrict__ adj, u16* __restrict__ es,
               float* __restrict__ msum)
{
  const int b = blockIdx.y, i = blockIdx.x;
  const int tid = threadIdx.x;
  const int c = tid & 31;          // channel chunk: channels c*8 .. c*8+7
  const int g = tid >> 5;          // 0..7 (w sub-group)
  __shared__ float red[8][256];
  float accv[8] = {0.f, 0.f, 0.f, 0.f, 0.f, 0.f, 0.f, 0.f};
  const long base_bi = ((long)(b * 128 + i)) * 128;
  for (int w0 = 0; w0 < 128; w0 += 8) {
    const int w = w0 + g;
    const float a = adj[base_bi + w];
    const float s = 1.f / (1.f + __expf(-a));
    const short8 ev = *(const short8*)(Em + (base_bi + w) * 256 + c * 8);
    const float* hp = Hm + ((long)(b * 128 + w)) * 256 + c * 8;
    u16 mb[8];
#pragma unroll
    for (int j = 0; j < 8; ++j) {
      float x = bf2f(((const u16*)&ev)[j]) + hp[j];
      x = fmaxf(x, 0.f) * s;
      accv[j] += x;
      mb[j] = f2bf(x);
    }
    *(short8*)(es + (((long)(b * 128 + w)) * 128 + i) * 256 + c * 8) = *(short8*)mb;
  }
#pragma unroll
  for (int j = 0; j < 8; ++j) red[g][c * 8 + j] = accv[j];
  __syncthreads();
  float s = 0.f;
#pragma unroll
  for (int gg = 0; gg < 8; ++gg) s += red[gg][tid];
  msum[((long)(b * 128 + i)) * 256 + tid] = s;
}

// GRU combine (in-place h update)
__global__ void gru_k(const float* __restrict__ gi, const float* __restrict__ gh,
                      float* __restrict__ h)
{
  const int n = blockIdx.x;     // 0..1023
  const int d = threadIdx.x;    // 0..255
  const int base = n * 768;
  const float r  = 1.f / (1.f + __expf(-(gi[base + d] + gh[base + d])));
  const float z  = 1.f / (1.f + __expf(-(gi[base + 256 + d] + gh[base + 256 + d])));
  const float nn = tanhf(gi[base + 512 + d] + r * gh[base + 512 + d]);
  const int hi = n * 256 + d;
  h[hi] = (1.f - z) * nn + z * h[hi];
}

extern "C" void kernel_launch(void* const* d_in, const int* in_sizes, int n_in,
                              void* d_out, int out_size, void* d_ws, size_t ws_size,
                              hipStream_t stream)
{
  const float* edge = (const float*)d_in[0];
  const float* node = (const float*)d_in[1];
  const float* W_er = (const float*)d_in[2];
  const float* b_er = (const float*)d_in[3];
  const float* W_nr = (const float*)d_in[4];
  const float* b_nr = (const float*)d_in[5];
  const float* Wl1  = (const float*)d_in[6];
  const float* bl1  = (const float*)d_in[7];
  const float* Wl2  = (const float*)d_in[8];
  const float* bl2  = (const float*)d_in[9];
  const float* Wl3  = (const float*)d_in[10];
  const float* bl3  = (const float*)d_in[11];
  const float* W_m  = (const float*)d_in[12];
  const float* b_m  = (const float*)d_in[13];
  const float* W_ih = (const float*)d_in[14];
  const float* b_ih = (const float*)d_in[15];
  const float* W_hh = (const float*)d_in[16];
  const float* b_hh = (const float*)d_in[17];
  const float* W_r  = (const float*)d_in[18];
  const float* b_r  = (const float*)d_in[19];
  (void)in_sizes; (void)n_in; (void)out_size; (void)ws_size;

  float* out_adj = (float*)d_out;            // [8,128,128] = 131072 floats
  float* out_lab = (float*)d_out + 131072;   // [8,128,117]

  char* ws = (char*)d_ws;
  size_t off = 0;
  auto alloc = [&](size_t bytes) -> void* {
    void* p = ws + off; off += (bytes + 255) & ~(size_t)255; return p;
  };
  const long E = 131072;                       // B*N*N edges
  u16*   es   = (u16*)  alloc(E * 256 * 2);    // ef (layer0) then e_state, bf16
  u16*   Em   = (u16*)  alloc(E * 256 * 2);    // edge half of message, bf16
  u16*   x1   = (u16*)  alloc(E * 512 * 2);    // link hidden 1, bf16
  float* Hm   = (float*)alloc(1024 * 256 * 4);
  float* hbuf = (float*)alloc(1024 * 256 * 4);
  float* msum = (float*)alloc(1024 * 256 * 4);
  float* gi   = (float*)alloc(1024 * 768 * 4);
  float* gh   = (float*)alloc(1024 * 768 * 4);
  u16*   Werp = (u16*)  alloc(256 * 224 * 2);  // bf16 (adj path)
  u16*   Wl1b = (u16*)  alloc(512 * 256 * 2);
  u16*   Wl2b = (u16*)  alloc(512 * 512 * 2);
  float* Wcf  = (float*)alloc(256 * 224 * 4);
  float* cmb  = (float*)alloc(256 * 4);
  // split hi/lo weight pairs (h path)
  u16* Wc_h  = (u16*)alloc(256 * 224 * 2); u16* Wc_l  = (u16*)alloc(256 * 224 * 2);
  u16* Wnr_h = (u16*)alloc(256 * 128 * 2); u16* Wnr_l = (u16*)alloc(256 * 128 * 2);
  u16* Wmh_h = (u16*)alloc(256 * 256 * 2); u16* Wmh_l = (u16*)alloc(256 * 256 * 2);
  u16* Wih_h = (u16*)alloc(768 * 256 * 2); u16* Wih_l = (u16*)alloc(768 * 256 * 2);
  u16* Whh_h = (u16*)alloc(768 * 256 * 2); u16* Whh_l = (u16*)alloc(768 * 256 * 2);
  u16* Wr_h  = (u16*)alloc(117 * 256 * 2); u16* Wr_l  = (u16*)alloc(117 * 256 * 2);

  auto cast = [&](u16* dst, const float* src, int rows, int sc, int dc,
                  int stride, int coff) {
    int total = rows * dc;
    cast_pad_k<<<(total + 255) / 256, 256, 0, stream>>>(dst, src, rows, sc, dc,
                                                        stride, coff);
  };
  auto split = [&](u16* dh, u16* dl, const float* src, int rows, int sc, int dc,
                   int stride, int coff) {
    int total = rows * dc;
    cast_split_k<<<(total + 255) / 256, 256, 0, stream>>>(dh, dl, src, rows, sc,
                                                          dc, stride, coff);
  };
  cast(Werp, W_er, 256, 200, 224, 200, 0);
  cast(Wl1b, Wl1, 512, 256, 256, 256, 0);
  cast(Wl2b, Wl2, 512, 512, 512, 512, 0);
  wc_k<<<256, 256, 0, stream>>>(Wcf, cmb, W_m, W_er, b_er, b_m);
  split(Wc_h,  Wc_l,  Wcf, 256, 224, 224, 224, 0);
  split(Wnr_h, Wnr_l, W_nr, 256, 100, 128, 100, 0);
  split(Wmh_h, Wmh_l, W_m, 256, 256, 256, 512, 0);   // W_m[:, :256]
  split(Wih_h, Wih_l, W_ih, 768, 256, 256, 256, 0);
  split(Whh_h, Whh_l, W_hh, 768, 256, 256, 256, 0);
  split(Wr_h,  Wr_l,  W_r, 117, 256, 256, 256, 0);

  const dim3 blk(256);
  // ef = bf16(edge @ W_er^T + b_er)   (e_state for layer 0; adj path, bf16 ok)
  gemm_k<true, true, false, false><<<dim3(1024, 2), blk, 0, stream>>>(
      edge, Werp, b_er, es, nullptr, nullptr, 256, 224, 200, 200, 256);
  // Em = bf16(edge @ W_c^T + c_m)     (message edge-half; split precision)
  gemm_sp_k<true><<<dim3(1024, 2), blk, 0, stream>>>(
      edge, Wc_h, Wc_l, cmb, Em, 256, 224, 200, 200, 256);
  // h0 = node @ W_nr^T + b_nr  (split)
  gemm_sp_k<false><<<dim3(8, 2), blk, 0, stream>>>(
      node, Wnr_h, Wnr_l, b_nr, hbuf, 256, 128, 100, 100, 256);

  for (int p = 0; p < 3; ++p) {
    fill_k<<<512, 256, 0, stream>>>(out_adj, bl3, 131072);
    // Hm = h @ W_mh^T  (split)
    gemm_sp_k<false><<<dim3(8, 2), blk, 0, stream>>>(
        hbuf, Wmh_h, Wmh_l, nullptr, Hm, 256, 256, 256, 256, 256);
    // x1 = relu(e_state @ Wl1^T + bl1)   (adj path, bf16)
    gemm_k<false, true, true, false><<<dim3(1024, 4), blk, 0, stream>>>(
        es, Wl1b, bl1, x1, nullptr, nullptr, 512, 256, 256, 256, 512);
    // adj += sum_col relu(x1 @ Wl2^T + bl2)[.,col] * Wl3[col]
    gemm_k<false, false, true, true><<<dim3(1024, 4), blk, 0, stream>>>(
        x1, Wl2b, bl2, nullptr, out_adj, Wl3, 512, 512, 512, 512, 0);
    // messages, transpose-scatter into e_state, aggregate msum
    message_k<<<dim3(128, 8), blk, 0, stream>>>(Em, Hm, out_adj, es, msum);
    // GRU gates (split precision — msum is O(18), bf16 staging was the bug)
    gemm_sp_k<false><<<dim3(8, 6), blk, 0, stream>>>(
        msum, Wih_h, Wih_l, b_ih, gi, 768, 256, 256, 256, 768);
    gemm_sp_k<false><<<dim3(8, 6), blk, 0, stream>>>(
        hbuf, Whh_h, Whh_l, b_hh, gh, 768, 256, 256, 256, 768);
    gru_k<<<1024, 256, 0, stream>>>(gi, gh, hbuf);
  }
  // labels = h @ W_r^T + b_r  (split)
  gemm_sp_k<false><<<dim3(8, 1), blk, 0, stream>>>(
      hbuf, Wr_h, Wr_l, b_r, out_lab, 117, 256, 256, 256, 117);
}

// Round 3
// 1666.046 us; speedup vs baseline: 1.0154x; 1.0154x over previous
//
#include <hip/hip_runtime.h>
#include <math.h>

typedef unsigned short u16;
typedef __attribute__((ext_vector_type(8))) short short8;
typedef __attribute__((ext_vector_type(4))) float floatx4;

__device__ __forceinline__ float bf2f(u16 u) {
  union { unsigned int i; float f; } v; v.i = ((unsigned int)u) << 16; return v.f;
}
__device__ __forceinline__ u16 f2bf(float f) {
  union { unsigned int i; float f; } v; v.f = f;
  unsigned int i = v.i;
  unsigned int lsb = (i >> 16) & 1u;
  i += 0x7fffu + lsb;          // round-to-nearest-even
  return (u16)(i >> 16);
}

// ---------------------------------------------------------------------------
// Generic bf16 MFMA GEMM (used for ef only now).
// ---------------------------------------------------------------------------
template<bool A_F32, bool OUT_BF16, bool RELU>
__global__ __launch_bounds__(256, 2)
void gemm_k(const void* __restrict__ Ap, const u16* __restrict__ Bw,
            const float* __restrict__ bias, void* __restrict__ Cp,
            int N, int K_loop, int K_src, int lda, int ldc)
{
  __shared__ __align__(16) u16 As[128 * 40];
  __shared__ __align__(16) u16 Bs[128 * 40];
  const int tid  = threadIdx.x;
  const int m0   = blockIdx.x * 128;
  const int n0   = blockIdx.y * 128;
  const int lane = tid & 63;
  const int wv   = tid >> 6;
  const int wm   = wv & 1;
  const int wn   = wv >> 1;
  const int q    = lane >> 4;
  const int cl   = lane & 15;

  floatx4 acc[4][4];
#pragma unroll
  for (int i = 0; i < 4; ++i)
#pragma unroll
    for (int j = 0; j < 4; ++j)
      acc[i][j] = (floatx4){0.f, 0.f, 0.f, 0.f};

  const int srow = tid >> 1;
  const int scol = (tid & 1) * 16;

  for (int kb = 0; kb < K_loop; kb += 32) {
    {
      const long r = (long)(m0 + srow);
      u16* dst = &As[srow * 40 + scol];
      if (A_F32) {
        const float* A = (const float*)Ap;
#pragma unroll
        for (int j = 0; j < 16; ++j) {
          int kg = kb + scol + j;
          float v = (kg < K_src) ? A[r * lda + kg] : 0.f;
          dst[j] = f2bf(v);
        }
      } else {
        const u16* A = (const u16*)Ap;
        const short8* s = (const short8*)(A + r * lda + kb + scol);
        ((short8*)dst)[0] = s[0];
        ((short8*)dst)[1] = s[1];
      }
    }
    {
      const int n = n0 + srow;
      u16* dst = &Bs[srow * 40 + scol];
      if (n < N) {
        const short8* s = (const short8*)(Bw + (long)n * K_loop + kb + scol);
        ((short8*)dst)[0] = s[0];
        ((short8*)dst)[1] = s[1];
      } else {
#pragma unroll
        for (int j = 0; j < 16; ++j) dst[j] = 0;
      }
    }
    __syncthreads();

    short8 af[4], bfr[4];
#pragma unroll
    for (int mi = 0; mi < 4; ++mi)
      af[mi] = *(const short8*)&As[(wm * 64 + mi * 16 + cl) * 40 + q * 8];
#pragma unroll
    for (int ni = 0; ni < 4; ++ni)
      bfr[ni] = *(const short8*)&Bs[(wn * 64 + ni * 16 + cl) * 40 + q * 8];
#pragma unroll
    for (int mi = 0; mi < 4; ++mi)
#pragma unroll
      for (int ni = 0; ni < 4; ++ni)
        acc[mi][ni] = __builtin_amdgcn_mfma_f32_16x16x32_bf16(af[mi], bfr[ni], acc[mi][ni], 0, 0, 0);
    __syncthreads();
  }

#pragma unroll
  for (int mi = 0; mi < 4; ++mi) {
    const int row = m0 + wm * 64 + mi * 16 + q * 4;
#pragma unroll
    for (int ni = 0; ni < 4; ++ni) {
      const int col = n0 + wn * 64 + ni * 16 + cl;
      if (col < N) {
        const float b = bias ? bias[col] : 0.f;
#pragma unroll
        for (int r = 0; r < 4; ++r) {
          float v = acc[mi][ni][r] + b;
          if (RELU) v = fmaxf(v, 0.f);
          const long off = (long)(row + r) * ldc + col;
          if (OUT_BF16) ((u16*)Cp)[off] = f2bf(v);
          else          ((float*)Cp)[off] = v;
        }
      }
    }
  }
}

// ---------------------------------------------------------------------------
// Fused link MLP: per block of 64 edge rows,
//   phase1: x1[64x512] = relu(es[64x256] @ Wl1^T + bl1)  -> LDS (bf16, swizzled)
//   phase2: adj[64]    = bl3 + sum_col relu(x1 @ Wl2^T + bl2)[r,col] * wl3[col]
// A-fragments read direct from global (L1/L2-hot), B-fragments direct from
// global (weights L2-resident), register double-buffered. x1 never hits HBM.
// ---------------------------------------------------------------------------
__global__ __launch_bounds__(256, 2)
void link_k(const u16* __restrict__ es, const u16* __restrict__ Wl1b,
            const float* __restrict__ bl1, const u16* __restrict__ Wl2b,
            const float* __restrict__ bl2, const float* __restrict__ wl3,
            const float* __restrict__ bl3, float* __restrict__ adj)
{
  __shared__ __align__(16) u16 x1b[64 * 512];   // 64 KB, XOR-swizzled chunks
  const int tid  = threadIdx.x;
  const int lane = tid & 63;
  const int wv   = tid >> 6;        // wave 0..3 -> 128-col slice
  const int q    = lane >> 4;
  const int cl   = lane & 15;
  const int nw0  = wv * 128;
  const long r0  = (long)blockIdx.x * 64;

  floatx4 acc[4][8];
#pragma unroll
  for (int mi = 0; mi < 4; ++mi)
#pragma unroll
    for (int ni = 0; ni < 8; ++ni)
      acc[mi][ni] = (floatx4){0.f, 0.f, 0.f, 0.f};

  // ---------------- phase 1: x1 = relu(es @ Wl1^T + bl1) ----------------
  {
    short8 b0[8], b1[8];
#pragma unroll
    for (int ni = 0; ni < 8; ++ni)
      b0[ni] = *(const short8*)(Wl1b + (nw0 + ni * 16 + cl) * 256 + q * 8);
#pragma unroll
    for (int ks = 0; ks < 8; ++ks) {
      short8* bc = (ks & 1) ? b1 : b0;
      short8* bn = (ks & 1) ? b0 : b1;
      if (ks < 7) {
        const int kb = (ks + 1) * 32;
#pragma unroll
        for (int ni = 0; ni < 8; ++ni)
          bn[ni] = *(const short8*)(Wl1b + (nw0 + ni * 16 + cl) * 256 + kb + q * 8);
      }
      short8 a[4];
#pragma unroll
      for (int mi = 0; mi < 4; ++mi)
        a[mi] = *(const short8*)(es + (r0 + mi * 16 + cl) * 256 + ks * 32 + q * 8);
#pragma unroll
      for (int mi = 0; mi < 4; ++mi)
#pragma unroll
        for (int ni = 0; ni < 8; ++ni)
          acc[mi][ni] = __builtin_amdgcn_mfma_f32_16x16x32_bf16(a[mi], bc[ni], acc[mi][ni], 0, 0, 0);
    }
  }
  // epilogue 1: write x1 (bf16) into swizzled LDS
#pragma unroll
  for (int mi = 0; mi < 4; ++mi)
#pragma unroll
    for (int ni = 0; ni < 8; ++ni) {
      const int col = nw0 + ni * 16 + cl;
      const float bb = bl1[col];
      const int chunk = col >> 3;
#pragma unroll
      for (int r = 0; r < 4; ++r) {
        const int row = mi * 16 + q * 4 + r;
        const float v = fmaxf(acc[mi][ni][r] + bb, 0.f);
        x1b[row * 512 + (((chunk ^ (row & 7)) << 3) | (col & 7))] = f2bf(v);
      }
    }
#pragma unroll
  for (int mi = 0; mi < 4; ++mi)
#pragma unroll
    for (int ni = 0; ni < 8; ++ni)
      acc[mi][ni] = (floatx4){0.f, 0.f, 0.f, 0.f};
  __syncthreads();

  // ---------------- phase 2: acc = x1 @ Wl2^T ----------------
  {
    short8 b0[8], b1[8];
#pragma unroll
    for (int ni = 0; ni < 8; ++ni)
      b0[ni] = *(const short8*)(Wl2b + (nw0 + ni * 16 + cl) * 512 + q * 8);
#pragma unroll
    for (int ks = 0; ks < 16; ++ks) {
      short8* bc = (ks & 1) ? b1 : b0;
      short8* bn = (ks & 1) ? b0 : b1;
      if (ks < 15) {
        const int kb = (ks + 1) * 32;
#pragma unroll
        for (int ni = 0; ni < 8; ++ni)
          bn[ni] = *(const short8*)(Wl2b + (nw0 + ni * 16 + cl) * 512 + kb + q * 8);
      }
      short8 a[4];
#pragma unroll
      for (int mi = 0; mi < 4; ++mi) {
        const int row = mi * 16 + cl;
        const int chunk = ks * 4 + q;
        a[mi] = *(const short8*)&x1b[row * 512 + ((chunk ^ (row & 7)) << 3)];
      }
#pragma unroll
      for (int mi = 0; mi < 4; ++mi)
#pragma unroll
        for (int ni = 0; ni < 8; ++ni)
          acc[mi][ni] = __builtin_amdgcn_mfma_f32_16x16x32_bf16(a[mi], bc[ni], acc[mi][ni], 0, 0, 0);
    }
  }

  // epilogue 2: relu(+bl2), dot wl3, reduce to adj
  float pv[4][4];
#pragma unroll
  for (int mi = 0; mi < 4; ++mi)
#pragma unroll
    for (int r = 0; r < 4; ++r) pv[mi][r] = 0.f;
#pragma unroll
  for (int mi = 0; mi < 4; ++mi)
#pragma unroll
    for (int ni = 0; ni < 8; ++ni) {
      const int col = nw0 + ni * 16 + cl;
      const float bb = bl2[col];
      const float w3 = wl3[col];
#pragma unroll
      for (int r = 0; r < 4; ++r) {
        const float v = fmaxf(acc[mi][ni][r] + bb, 0.f);
        pv[mi][r] += v * w3;
      }
    }
  __syncthreads();                    // all x1b reads done; reuse as reduce buf
  float* pf = (float*)x1b;            // [4 waves][64 rows]
#pragma unroll
  for (int mi = 0; mi < 4; ++mi)
#pragma unroll
    for (int r = 0; r < 4; ++r) {
      float p = pv[mi][r];
#pragma unroll
      for (int off = 1; off < 16; off <<= 1)
        p += __shfl_xor(p, off, 64);
      if (cl == 0) pf[wv * 64 + mi * 16 + q * 4 + r] = p;
    }
  __syncthreads();
  if (tid < 64)
    adj[r0 + tid] = bl3[0] + pf[tid] + pf[64 + tid] + pf[128 + tid] + pf[192 + tid];
}

// ---------------------------------------------------------------------------
// Split-precision MFMA GEMM (~fp32 accuracy) for the h path.
// ---------------------------------------------------------------------------
template<bool OUT_BF16>
__global__ __launch_bounds__(256, 2)
void gemm_sp_k(const float* __restrict__ A, const u16* __restrict__ Bh,
               const u16* __restrict__ Bl, const float* __restrict__ bias,
               void* __restrict__ Cp,
               int N, int K_loop, int K_src, int lda, int ldc)
{
  __shared__ __align__(16) u16 Ash[128 * 40];
  __shared__ __align__(16) u16 Asl[128 * 40];
  __shared__ __align__(16) u16 Bsh[128 * 40];
  __shared__ __align__(16) u16 Bsl[128 * 40];
  const int tid  = threadIdx.x;
  const int m0   = blockIdx.x * 128;
  const int n0   = blockIdx.y * 128;
  const int lane = tid & 63;
  const int wv   = tid >> 6;
  const int wm   = wv & 1;
  const int wn   = wv >> 1;
  const int q    = lane >> 4;
  const int cl   = lane & 15;

  floatx4 acc[4][4];
#pragma unroll
  for (int i = 0; i < 4; ++i)
#pragma unroll
    for (int j = 0; j < 4; ++j)
      acc[i][j] = (floatx4){0.f, 0.f, 0.f, 0.f};

  const int srow = tid >> 1;
  const int scol = (tid & 1) * 16;

  for (int kb = 0; kb < K_loop; kb += 32) {
    {
      const long r = (long)(m0 + srow);
      u16* dh = &Ash[srow * 40 + scol];
      u16* dl = &Asl[srow * 40 + scol];
#pragma unroll
      for (int j = 0; j < 16; ++j) {
        int kg = kb + scol + j;
        float v = (kg < K_src) ? A[r * lda + kg] : 0.f;
        u16 hi = f2bf(v);
        dh[j] = hi;
        dl[j] = f2bf(v - bf2f(hi));
      }
    }
    {
      const int n = n0 + srow;
      u16* dh = &Bsh[srow * 40 + scol];
      u16* dl = &Bsl[srow * 40 + scol];
      if (n < N) {
        const short8* sh = (const short8*)(Bh + (long)n * K_loop + kb + scol);
        const short8* sl = (const short8*)(Bl + (long)n * K_loop + kb + scol);
        ((short8*)dh)[0] = sh[0]; ((short8*)dh)[1] = sh[1];
        ((short8*)dl)[0] = sl[0]; ((short8*)dl)[1] = sl[1];
      } else {
#pragma unroll
        for (int j = 0; j < 16; ++j) { dh[j] = 0; dl[j] = 0; }
      }
    }
    __syncthreads();

    short8 ah[4], al[4], bh[4], bl[4];
#pragma unroll
    for (int mi = 0; mi < 4; ++mi) {
      ah[mi] = *(const short8*)&Ash[(wm * 64 + mi * 16 + cl) * 40 + q * 8];
      al[mi] = *(const short8*)&Asl[(wm * 64 + mi * 16 + cl) * 40 + q * 8];
    }
#pragma unroll
    for (int ni = 0; ni < 4; ++ni) {
      bh[ni] = *(const short8*)&Bsh[(wn * 64 + ni * 16 + cl) * 40 + q * 8];
      bl[ni] = *(const short8*)&Bsl[(wn * 64 + ni * 16 + cl) * 40 + q * 8];
    }
#pragma unroll
    for (int mi = 0; mi < 4; ++mi)
#pragma unroll
      for (int ni = 0; ni < 4; ++ni) {
        acc[mi][ni] = __builtin_amdgcn_mfma_f32_16x16x32_bf16(ah[mi], bh[ni], acc[mi][ni], 0, 0, 0);
        acc[mi][ni] = __builtin_amdgcn_mfma_f32_16x16x32_bf16(al[mi], bh[ni], acc[mi][ni], 0, 0, 0);
        acc[mi][ni] = __builtin_amdgcn_mfma_f32_16x16x32_bf16(ah[mi], bl[ni], acc[mi][ni], 0, 0, 0);
      }
    __syncthreads();
  }

#pragma unroll
  for (int mi = 0; mi < 4; ++mi) {
    const int row = m0 + wm * 64 + mi * 16 + q * 4;
#pragma unroll
    for (int ni = 0; ni < 4; ++ni) {
      const int col = n0 + wn * 64 + ni * 16 + cl;
      if (col < N) {
        const float b = bias ? bias[col] : 0.f;
#pragma unroll
        for (int r = 0; r < 4; ++r) {
          float v = acc[mi][ni][r] + b;
          const long off = (long)(row + r) * ldc + col;
          if (OUT_BF16) ((u16*)Cp)[off] = f2bf(v);
          else          ((float*)Cp)[off] = v;
        }
      }
    }
  }
}

__global__ void cast_pad_k(u16* __restrict__ dst, const float* __restrict__ src,
                           int rows, int src_cols, int dst_cols, int src_stride,
                           int col_off)
{
  int idx = blockIdx.x * blockDim.x + threadIdx.x;
  int total = rows * dst_cols;
  if (idx >= total) return;
  int r = idx / dst_cols, c = idx - r * dst_cols;
  float v = (c < src_cols) ? src[r * src_stride + col_off + c] : 0.f;
  dst[idx] = f2bf(v);
}

__global__ void cast_split_k(u16* __restrict__ dh, u16* __restrict__ dl,
                             const float* __restrict__ src,
                             int rows, int src_cols, int dst_cols, int src_stride,
                             int col_off)
{
  int idx = blockIdx.x * blockDim.x + threadIdx.x;
  int total = rows * dst_cols;
  if (idx >= total) return;
  int r = idx / dst_cols, c = idx - r * dst_cols;
  float v = (c < src_cols) ? src[r * src_stride + col_off + c] : 0.f;
  u16 hi = f2bf(v);
  dh[idx] = hi;
  dl[idx] = f2bf(v - bf2f(hi));
}

// Wcf = W_me @ W_er (fp32, [256 x 224] zero-padded); c_m = W_me @ b_er + b_m
__global__ void wc_k(float* __restrict__ Wcf, float* __restrict__ cm,
                     const float* __restrict__ W_m, const float* __restrict__ W_er,
                     const float* __restrict__ b_er, const float* __restrict__ b_m)
{
  int o = blockIdx.x;
  int t = threadIdx.x;
  __shared__ float wme[256];
  wme[t] = W_m[o * 512 + 256 + t];
  __syncthreads();
  if (t < 224) {
    float s = 0.f;
    if (t < 200) {
      for (int c = 0; c < 256; ++c) s += wme[c] * W_er[c * 200 + t];
    }
    Wcf[o * 224 + t] = s;
  }
  if (t == 0) {
    float s = 0.f;
    for (int c = 0; c < 256; ++c) s += wme[c] * b_er[c];
    cm[o] = s + b_m[o];
  }
}

// Per-edge message + transpose-scatter + per-target aggregation.
__global__ __launch_bounds__(256)
void message_k(const u16* __restrict__ Em, const float* __restrict__ Hm,
               const float* __restrict__ adj, u16* __restrict__ es,
               float* __restrict__ msum)
{
  const int b = blockIdx.y, i = blockIdx.x;
  const int tid = threadIdx.x;
  const int c = tid & 31;
  const int g = tid >> 5;
  __shared__ float red[8][256];
  float accv[8] = {0.f, 0.f, 0.f, 0.f, 0.f, 0.f, 0.f, 0.f};
  const long base_bi = ((long)(b * 128 + i)) * 128;
  for (int w0 = 0; w0 < 128; w0 += 8) {
    const int w = w0 + g;
    const float a = adj[base_bi + w];
    const float s = 1.f / (1.f + __expf(-a));
    const short8 ev = *(const short8*)(Em + (base_bi + w) * 256 + c * 8);
    const float* hp = Hm + ((long)(b * 128 + w)) * 256 + c * 8;
    u16 mb[8];
#pragma unroll
    for (int j = 0; j < 8; ++j) {
      float x = bf2f(((const u16*)&ev)[j]) + hp[j];
      x = fmaxf(x, 0.f) * s;
      accv[j] += x;
      mb[j] = f2bf(x);
    }
    *(short8*)(es + (((long)(b * 128 + w)) * 128 + i) * 256 + c * 8) = *(short8*)mb;
  }
#pragma unroll
  for (int j = 0; j < 8; ++j) red[g][c * 8 + j] = accv[j];
  __syncthreads();
  float s = 0.f;
#pragma unroll
  for (int gg = 0; gg < 8; ++gg) s += red[gg][tid];
  msum[((long)(b * 128 + i)) * 256 + tid] = s;
}

__global__ void gru_k(const float* __restrict__ gi, const float* __restrict__ gh,
                      float* __restrict__ h)
{
  const int n = blockIdx.x;
  const int d = threadIdx.x;
  const int base = n * 768;
  const float r  = 1.f / (1.f + __expf(-(gi[base + d] + gh[base + d])));
  const float z  = 1.f / (1.f + __expf(-(gi[base + 256 + d] + gh[base + 256 + d])));
  const float nn = tanhf(gi[base + 512 + d] + r * gh[base + 512 + d]);
  const int hi = n * 256 + d;
  h[hi] = (1.f - z) * nn + z * h[hi];
}

extern "C" void kernel_launch(void* const* d_in, const int* in_sizes, int n_in,
                              void* d_out, int out_size, void* d_ws, size_t ws_size,
                              hipStream_t stream)
{
  const float* edge = (const float*)d_in[0];
  const float* node = (const float*)d_in[1];
  const float* W_er = (const float*)d_in[2];
  const float* b_er = (const float*)d_in[3];
  const float* W_nr = (const float*)d_in[4];
  const float* b_nr = (const float*)d_in[5];
  const float* Wl1  = (const float*)d_in[6];
  const float* bl1  = (const float*)d_in[7];
  const float* Wl2  = (const float*)d_in[8];
  const float* bl2  = (const float*)d_in[9];
  const float* Wl3  = (const float*)d_in[10];
  const float* bl3  = (const float*)d_in[11];
  const float* W_m  = (const float*)d_in[12];
  const float* b_m  = (const float*)d_in[13];
  const float* W_ih = (const float*)d_in[14];
  const float* b_ih = (const float*)d_in[15];
  const float* W_hh = (const float*)d_in[16];
  const float* b_hh = (const float*)d_in[17];
  const float* W_r  = (const float*)d_in[18];
  const float* b_r  = (const float*)d_in[19];
  (void)in_sizes; (void)n_in; (void)out_size; (void)ws_size;

  float* out_adj = (float*)d_out;            // [8,128,128]
  float* out_lab = (float*)d_out + 131072;   // [8,128,117]

  char* ws = (char*)d_ws;
  size_t off = 0;
  auto alloc = [&](size_t bytes) -> void* {
    void* p = ws + off; off += (bytes + 255) & ~(size_t)255; return p;
  };
  const long E = 131072;
  u16*   es   = (u16*)  alloc(E * 256 * 2);
  u16*   Em   = (u16*)  alloc(E * 256 * 2);
  float* Hm   = (float*)alloc(1024 * 256 * 4);
  float* hbuf = (float*)alloc(1024 * 256 * 4);
  float* msum = (float*)alloc(1024 * 256 * 4);
  float* gi   = (float*)alloc(1024 * 768 * 4);
  float* gh   = (float*)alloc(1024 * 768 * 4);
  u16*   Werp = (u16*)  alloc(256 * 224 * 2);
  u16*   Wl1b = (u16*)  alloc(512 * 256 * 2);
  u16*   Wl2b = (u16*)  alloc(512 * 512 * 2);
  float* Wcf  = (float*)alloc(256 * 224 * 4);
  float* cmb  = (float*)alloc(256 * 4);
  u16* Wc_h  = (u16*)alloc(256 * 224 * 2); u16* Wc_l  = (u16*)alloc(256 * 224 * 2);
  u16* Wnr_h = (u16*)alloc(256 * 128 * 2); u16* Wnr_l = (u16*)alloc(256 * 128 * 2);
  u16* Wmh_h = (u16*)alloc(256 * 256 * 2); u16* Wmh_l = (u16*)alloc(256 * 256 * 2);
  u16* Wih_h = (u16*)alloc(768 * 256 * 2); u16* Wih_l = (u16*)alloc(768 * 256 * 2);
  u16* Whh_h = (u16*)alloc(768 * 256 * 2); u16* Whh_l = (u16*)alloc(768 * 256 * 2);
  u16* Wr_h  = (u16*)alloc(117 * 256 * 2); u16* Wr_l  = (u16*)alloc(117 * 256 * 2);

  auto cast = [&](u16* dst, const float* src, int rows, int sc, int dc,
                  int stride, int coff) {
    int total = rows * dc;
    cast_pad_k<<<(total + 255) / 256, 256, 0, stream>>>(dst, src, rows, sc, dc,
                                                        stride, coff);
  };
  auto split = [&](u16* dh, u16* dl, const float* src, int rows, int sc, int dc,
                   int stride, int coff) {
    int total = rows * dc;
    cast_split_k<<<(total + 255) / 256, 256, 0, stream>>>(dh, dl, src, rows, sc,
                                                          dc, stride, coff);
  };
  cast(Werp, W_er, 256, 200, 224, 200, 0);
  cast(Wl1b, Wl1, 512, 256, 256, 256, 0);
  cast(Wl2b, Wl2, 512, 512, 512, 512, 0);
  wc_k<<<256, 256, 0, stream>>>(Wcf, cmb, W_m, W_er, b_er, b_m);
  split(Wc_h,  Wc_l,  Wcf, 256, 224, 224, 224, 0);
  split(Wnr_h, Wnr_l, W_nr, 256, 100, 128, 100, 0);
  split(Wmh_h, Wmh_l, W_m, 256, 256, 256, 512, 0);
  split(Wih_h, Wih_l, W_ih, 768, 256, 256, 256, 0);
  split(Whh_h, Whh_l, W_hh, 768, 256, 256, 256, 0);
  split(Wr_h,  Wr_l,  W_r, 117, 256, 256, 256, 0);

  const dim3 blk(256);
  // ef = bf16(edge @ W_er^T + b_er)   (e_state for layer 0)
  gemm_k<true, true, false><<<dim3(1024, 2), blk, 0, stream>>>(
      edge, Werp, b_er, es, 256, 224, 200, 200, 256);
  // Em = bf16(edge @ W_c^T + c_m)     (message edge-half; split precision)
  gemm_sp_k<true><<<dim3(1024, 2), blk, 0, stream>>>(
      edge, Wc_h, Wc_l, cmb, Em, 256, 224, 200, 200, 256);
  // h0 = node @ W_nr^T + b_nr
  gemm_sp_k<false><<<dim3(8, 2), blk, 0, stream>>>(
      node, Wnr_h, Wnr_l, b_nr, hbuf, 256, 128, 100, 100, 256);

  for (int p = 0; p < 3; ++p) {
    // Hm = h @ W_mh^T
    gemm_sp_k<false><<<dim3(8, 2), blk, 0, stream>>>(
        hbuf, Wmh_h, Wmh_l, nullptr, Hm, 256, 256, 256, 256, 256);
    // fused link MLP -> adj (writes out_adj directly, incl. bl3)
    link_k<<<2048, blk, 0, stream>>>(es, Wl1b, bl1, Wl2b, bl2, Wl3, bl3, out_adj);
    // messages, transpose-scatter into e_state, aggregate msum
    message_k<<<dim3(128, 8), blk, 0, stream>>>(Em, Hm, out_adj, es, msum);
    // GRU gates
    gemm_sp_k<false><<<dim3(8, 6), blk, 0, stream>>>(
        msum, Wih_h, Wih_l, b_ih, gi, 768, 256, 256, 256, 768);
    gemm_sp_k<false><<<dim3(8, 6), blk, 0, stream>>>(
        hbuf, Whh_h, Whh_l, b_hh, gh, 768, 256, 256, 256, 768);
    gru_k<<<1024, 256, 0, stream>>>(gi, gh, hbuf);
  }
  // labels = h @ W_r^T + b_r
  gemm_sp_k<false><<<dim3(8, 1), blk, 0, stream>>>(
      hbuf, Wr_h, Wr_l, b_r, out_lab, 117, 256, 256, 256, 117);
}

// Round 4
// 1289.801 us; speedup vs baseline: 1.3116x; 1.2917x over previous
//
#include <hip/hip_runtime.h>
#include <math.h>

typedef unsigned short u16;
typedef __attribute__((ext_vector_type(8))) short short8;
typedef __attribute__((ext_vector_type(4))) short short4v;
typedef __attribute__((ext_vector_type(4))) float floatx4;

__device__ __forceinline__ float bf2f(u16 u) {
  union { unsigned int i; float f; } v; v.i = ((unsigned int)u) << 16; return v.f;
}
__device__ __forceinline__ u16 f2bf(float f) {
  union { unsigned int i; float f; } v; v.f = f;
  unsigned int i = v.i;
  unsigned int lsb = (i >> 16) & 1u;
  i += 0x7fffu + lsb;          // round-to-nearest-even
  return (u16)(i >> 16);
}

// ---------------------------------------------------------------------------
// Fused front GEMM: reads edge[E x 200] fp32 ONCE (coalesced float4),
// produces es = bf16(edge @ W_er^T + b_er) and Em = bf16(edge @ Wc^T + cm)
// in a single pass. Block = 64 rows; A tile bf16 in LDS (stride 232: 2-way
// free bank pattern); 4 waves x 128 cols over combined [ef | Em] 512-col
// space (wave-uniform output routing). Weights L2-resident, reg-dbuffed.
// ---------------------------------------------------------------------------
__global__ __launch_bounds__(256, 2)
void fused_front_k(const float* __restrict__ edge, const u16* __restrict__ Wcomb,
                   const float* __restrict__ b_er, const float* __restrict__ cmb,
                   u16* __restrict__ es, u16* __restrict__ Em)
{
  __shared__ __align__(16) u16 As[64 * 232];
  const int tid  = threadIdx.x;
  const int lane = tid & 63;
  const int wv   = tid >> 6;
  const int q    = lane >> 4;
  const int cl   = lane & 15;
  const long r0  = (long)blockIdx.x * 64;

  // zero k-pad cols 200..223 (224..231 never read)
  for (int z = tid; z < 64 * 24; z += 256) {
    const int zr = z / 24;
    As[zr * 232 + 200 + (z - zr * 24)] = 0;
  }
  // stage 64x200 fp32 -> bf16, fully coalesced (3200 float4)
  const float4* src = (const float4*)(edge + r0 * 200);
  for (int it = tid; it < 3200; it += 256) {
    const float4 v = src[it];
    const int row = it / 50;
    const int c4  = it - row * 50;
    u16 t[4] = { f2bf(v.x), f2bf(v.y), f2bf(v.z), f2bf(v.w) };
    *(short4v*)&As[row * 232 + c4 * 4] = *(short4v*)t;
  }
  __syncthreads();

  floatx4 acc[4][8];
#pragma unroll
  for (int mi = 0; mi < 4; ++mi)
#pragma unroll
    for (int ni = 0; ni < 8; ++ni)
      acc[mi][ni] = (floatx4){0.f, 0.f, 0.f, 0.f};

  short8 b0[8], b1[8];
#pragma unroll
  for (int ni = 0; ni < 8; ++ni)
    b0[ni] = *(const short8*)(Wcomb + (long)(wv * 128 + ni * 16 + cl) * 224 + q * 8);
#pragma unroll
  for (int ks = 0; ks < 7; ++ks) {
    short8* bc = (ks & 1) ? b1 : b0;
    short8* bn = (ks & 1) ? b0 : b1;
    if (ks < 6) {
      const int kb = (ks + 1) * 32;
#pragma unroll
      for (int ni = 0; ni < 8; ++ni)
        bn[ni] = *(const short8*)(Wcomb + (long)(wv * 128 + ni * 16 + cl) * 224 + kb + q * 8);
    }
    short8 a[4];
#pragma unroll
    for (int mi = 0; mi < 4; ++mi)
      a[mi] = *(const short8*)&As[(mi * 16 + cl) * 232 + ks * 32 + q * 8];
#pragma unroll
    for (int mi = 0; mi < 4; ++mi)
#pragma unroll
      for (int ni = 0; ni < 8; ++ni)
        acc[mi][ni] = __builtin_amdgcn_mfma_f32_16x16x32_bf16(a[mi], bc[ni], acc[mi][ni], 0, 0, 0);
  }

  // epilogue: waves 0,1 -> es (b_er); waves 2,3 -> Em (cm)
  const bool is_ef   = (wv < 2);
  const float* bias  = is_ef ? b_er : cmb;
  u16* dst           = is_ef ? es : Em;
  const int colbase  = (wv & 1) * 128;
#pragma unroll
  for (int mi = 0; mi < 4; ++mi)
#pragma unroll
    for (int ni = 0; ni < 8; ++ni) {
      const int col = colbase + ni * 16 + cl;
      const float bb = bias[col];
#pragma unroll
      for (int r = 0; r < 4; ++r) {
        const int row = mi * 16 + q * 4 + r;
        dst[(r0 + row) * 256 + col] = f2bf(acc[mi][ni][r] + bb);
      }
    }
}

// ---------------------------------------------------------------------------
// Fused link MLP: per block of 64 edge rows,
//   phase1: x1[64x512] = relu(es[64x256] @ Wl1^T + bl1)  -> LDS (bf16, swizzled)
//   phase2: adj[64]    = bl3 + sum_col relu(x1 @ Wl2^T + bl2)[r,col] * wl3[col]
// ---------------------------------------------------------------------------
__global__ __launch_bounds__(256, 2)
void link_k(const u16* __restrict__ es, const u16* __restrict__ Wl1b,
            const float* __restrict__ bl1, const u16* __restrict__ Wl2b,
            const float* __restrict__ bl2, const float* __restrict__ wl3,
            const float* __restrict__ bl3, float* __restrict__ adj)
{
  __shared__ __align__(16) u16 x1b[64 * 512];   // 64 KB, XOR-swizzled chunks
  const int tid  = threadIdx.x;
  const int lane = tid & 63;
  const int wv   = tid >> 6;        // wave 0..3 -> 128-col slice
  const int q    = lane >> 4;
  const int cl   = lane & 15;
  const int nw0  = wv * 128;
  const long r0  = (long)blockIdx.x * 64;

  floatx4 acc[4][8];
#pragma unroll
  for (int mi = 0; mi < 4; ++mi)
#pragma unroll
    for (int ni = 0; ni < 8; ++ni)
      acc[mi][ni] = (floatx4){0.f, 0.f, 0.f, 0.f};

  // ---------------- phase 1: x1 = relu(es @ Wl1^T + bl1) ----------------
  {
    short8 b0[8], b1[8];
#pragma unroll
    for (int ni = 0; ni < 8; ++ni)
      b0[ni] = *(const short8*)(Wl1b + (nw0 + ni * 16 + cl) * 256 + q * 8);
#pragma unroll
    for (int ks = 0; ks < 8; ++ks) {
      short8* bc = (ks & 1) ? b1 : b0;
      short8* bn = (ks & 1) ? b0 : b1;
      if (ks < 7) {
        const int kb = (ks + 1) * 32;
#pragma unroll
        for (int ni = 0; ni < 8; ++ni)
          bn[ni] = *(const short8*)(Wl1b + (nw0 + ni * 16 + cl) * 256 + kb + q * 8);
      }
      short8 a[4];
#pragma unroll
      for (int mi = 0; mi < 4; ++mi)
        a[mi] = *(const short8*)(es + (r0 + mi * 16 + cl) * 256 + ks * 32 + q * 8);
#pragma unroll
      for (int mi = 0; mi < 4; ++mi)
#pragma unroll
        for (int ni = 0; ni < 8; ++ni)
          acc[mi][ni] = __builtin_amdgcn_mfma_f32_16x16x32_bf16(a[mi], bc[ni], acc[mi][ni], 0, 0, 0);
    }
  }
  // epilogue 1: write x1 (bf16) into swizzled LDS
#pragma unroll
  for (int mi = 0; mi < 4; ++mi)
#pragma unroll
    for (int ni = 0; ni < 8; ++ni) {
      const int col = nw0 + ni * 16 + cl;
      const float bb = bl1[col];
      const int chunk = col >> 3;
#pragma unroll
      for (int r = 0; r < 4; ++r) {
        const int row = mi * 16 + q * 4 + r;
        const float v = fmaxf(acc[mi][ni][r] + bb, 0.f);
        x1b[row * 512 + (((chunk ^ (row & 7)) << 3) | (col & 7))] = f2bf(v);
      }
    }
#pragma unroll
  for (int mi = 0; mi < 4; ++mi)
#pragma unroll
    for (int ni = 0; ni < 8; ++ni)
      acc[mi][ni] = (floatx4){0.f, 0.f, 0.f, 0.f};
  __syncthreads();

  // ---------------- phase 2: acc = x1 @ Wl2^T ----------------
  {
    short8 b0[8], b1[8];
#pragma unroll
    for (int ni = 0; ni < 8; ++ni)
      b0[ni] = *(const short8*)(Wl2b + (nw0 + ni * 16 + cl) * 512 + q * 8);
#pragma unroll
    for (int ks = 0; ks < 16; ++ks) {
      short8* bc = (ks & 1) ? b1 : b0;
      short8* bn = (ks & 1) ? b0 : b1;
      if (ks < 15) {
        const int kb = (ks + 1) * 32;
#pragma unroll
        for (int ni = 0; ni < 8; ++ni)
          bn[ni] = *(const short8*)(Wl2b + (nw0 + ni * 16 + cl) * 512 + kb + q * 8);
      }
      short8 a[4];
#pragma unroll
      for (int mi = 0; mi < 4; ++mi) {
        const int row = mi * 16 + cl;
        const int chunk = ks * 4 + q;
        a[mi] = *(const short8*)&x1b[row * 512 + ((chunk ^ (row & 7)) << 3)];
      }
#pragma unroll
      for (int mi = 0; mi < 4; ++mi)
#pragma unroll
        for (int ni = 0; ni < 8; ++ni)
          acc[mi][ni] = __builtin_amdgcn_mfma_f32_16x16x32_bf16(a[mi], bc[ni], acc[mi][ni], 0, 0, 0);
    }
  }

  // epilogue 2: relu(+bl2), dot wl3, reduce to adj
  float pv[4][4];
#pragma unroll
  for (int mi = 0; mi < 4; ++mi)
#pragma unroll
    for (int r = 0; r < 4; ++r) pv[mi][r] = 0.f;
#pragma unroll
  for (int mi = 0; mi < 4; ++mi)
#pragma unroll
    for (int ni = 0; ni < 8; ++ni) {
      const int col = nw0 + ni * 16 + cl;
      const float bb = bl2[col];
      const float w3 = wl3[col];
#pragma unroll
      for (int r = 0; r < 4; ++r) {
        const float v = fmaxf(acc[mi][ni][r] + bb, 0.f);
        pv[mi][r] += v * w3;
      }
    }
  __syncthreads();                    // all x1b reads done; reuse as reduce buf
  float* pf = (float*)x1b;            // [4 waves][64 rows]
#pragma unroll
  for (int mi = 0; mi < 4; ++mi)
#pragma unroll
    for (int r = 0; r < 4; ++r) {
      float p = pv[mi][r];
#pragma unroll
      for (int off = 1; off < 16; off <<= 1)
        p += __shfl_xor(p, off, 64);
      if (cl == 0) pf[wv * 64 + mi * 16 + q * 4 + r] = p;
    }
  __syncthreads();
  if (tid < 64)
    adj[r0 + tid] = bl3[0] + pf[tid] + pf[64 + tid] + pf[128 + tid] + pf[192 + tid];
}

// ---------------------------------------------------------------------------
// Split-precision MFMA GEMM (~fp32 accuracy) for the h path.
// ---------------------------------------------------------------------------
template<bool OUT_BF16>
__global__ __launch_bounds__(256, 2)
void gemm_sp_k(const float* __restrict__ A, const u16* __restrict__ Bh,
               const u16* __restrict__ Bl, const float* __restrict__ bias,
               void* __restrict__ Cp,
               int N, int K_loop, int K_src, int lda, int ldc)
{
  __shared__ __align__(16) u16 Ash[128 * 40];
  __shared__ __align__(16) u16 Asl[128 * 40];
  __shared__ __align__(16) u16 Bsh[128 * 40];
  __shared__ __align__(16) u16 Bsl[128 * 40];
  const int tid  = threadIdx.x;
  const int m0   = blockIdx.x * 128;
  const int n0   = blockIdx.y * 128;
  const int lane = tid & 63;
  const int wv   = tid >> 6;
  const int wm   = wv & 1;
  const int wn   = wv >> 1;
  const int q    = lane >> 4;
  const int cl   = lane & 15;

  floatx4 acc[4][4];
#pragma unroll
  for (int i = 0; i < 4; ++i)
#pragma unroll
    for (int j = 0; j < 4; ++j)
      acc[i][j] = (floatx4){0.f, 0.f, 0.f, 0.f};

  const int srow = tid >> 1;
  const int scol = (tid & 1) * 16;

  for (int kb = 0; kb < K_loop; kb += 32) {
    {
      const long r = (long)(m0 + srow);
      u16* dh = &Ash[srow * 40 + scol];
      u16* dl = &Asl[srow * 40 + scol];
#pragma unroll
      for (int j = 0; j < 16; ++j) {
        int kg = kb + scol + j;
        float v = (kg < K_src) ? A[r * lda + kg] : 0.f;
        u16 hi = f2bf(v);
        dh[j] = hi;
        dl[j] = f2bf(v - bf2f(hi));
      }
    }
    {
      const int n = n0 + srow;
      u16* dh = &Bsh[srow * 40 + scol];
      u16* dl = &Bsl[srow * 40 + scol];
      if (n < N) {
        const short8* sh = (const short8*)(Bh + (long)n * K_loop + kb + scol);
        const short8* sl = (const short8*)(Bl + (long)n * K_loop + kb + scol);
        ((short8*)dh)[0] = sh[0]; ((short8*)dh)[1] = sh[1];
        ((short8*)dl)[0] = sl[0]; ((short8*)dl)[1] = sl[1];
      } else {
#pragma unroll
        for (int j = 0; j < 16; ++j) { dh[j] = 0; dl[j] = 0; }
      }
    }
    __syncthreads();

    short8 ah[4], al[4], bh[4], bl[4];
#pragma unroll
    for (int mi = 0; mi < 4; ++mi) {
      ah[mi] = *(const short8*)&Ash[(wm * 64 + mi * 16 + cl) * 40 + q * 8];
      al[mi] = *(const short8*)&Asl[(wm * 64 + mi * 16 + cl) * 40 + q * 8];
    }
#pragma unroll
    for (int ni = 0; ni < 4; ++ni) {
      bh[ni] = *(const short8*)&Bsh[(wn * 64 + ni * 16 + cl) * 40 + q * 8];
      bl[ni] = *(const short8*)&Bsl[(wn * 64 + ni * 16 + cl) * 40 + q * 8];
    }
#pragma unroll
    for (int mi = 0; mi < 4; ++mi)
#pragma unroll
      for (int ni = 0; ni < 4; ++ni) {
        acc[mi][ni] = __builtin_amdgcn_mfma_f32_16x16x32_bf16(ah[mi], bh[ni], acc[mi][ni], 0, 0, 0);
        acc[mi][ni] = __builtin_amdgcn_mfma_f32_16x16x32_bf16(al[mi], bh[ni], acc[mi][ni], 0, 0, 0);
        acc[mi][ni] = __builtin_amdgcn_mfma_f32_16x16x32_bf16(ah[mi], bl[ni], acc[mi][ni], 0, 0, 0);
      }
    __syncthreads();
  }

#pragma unroll
  for (int mi = 0; mi < 4; ++mi) {
    const int row = m0 + wm * 64 + mi * 16 + q * 4;
#pragma unroll
    for (int ni = 0; ni < 4; ++ni) {
      const int col = n0 + wn * 64 + ni * 16 + cl;
      if (col < N) {
        const float b = bias ? bias[col] : 0.f;
#pragma unroll
        for (int r = 0; r < 4; ++r) {
          float v = acc[mi][ni][r] + b;
          const long off = (long)(row + r) * ldc + col;
          if (OUT_BF16) ((u16*)Cp)[off] = f2bf(v);
          else          ((float*)Cp)[off] = v;
        }
      }
    }
  }
}

__global__ void cast_pad_k(u16* __restrict__ dst, const float* __restrict__ src,
                           int rows, int src_cols, int dst_cols, int src_stride,
                           int col_off)
{
  int idx = blockIdx.x * blockDim.x + threadIdx.x;
  int total = rows * dst_cols;
  if (idx >= total) return;
  int r = idx / dst_cols, c = idx - r * dst_cols;
  float v = (c < src_cols) ? src[r * src_stride + col_off + c] : 0.f;
  dst[idx] = f2bf(v);
}

__global__ void cast_split_k(u16* __restrict__ dh, u16* __restrict__ dl,
                             const float* __restrict__ src,
                             int rows, int src_cols, int dst_cols, int src_stride,
                             int col_off)
{
  int idx = blockIdx.x * blockDim.x + threadIdx.x;
  int total = rows * dst_cols;
  if (idx >= total) return;
  int r = idx / dst_cols, c = idx - r * dst_cols;
  float v = (c < src_cols) ? src[r * src_stride + col_off + c] : 0.f;
  u16 hi = f2bf(v);
  dh[idx] = hi;
  dl[idx] = f2bf(v - bf2f(hi));
}

// Wcf = W_me @ W_er (fp32, [256 x 224] zero-padded); c_m = W_me @ b_er + b_m
__global__ void wc_k(float* __restrict__ Wcf, float* __restrict__ cm,
                     const float* __restrict__ W_m, const float* __restrict__ W_er,
                     const float* __restrict__ b_er, const float* __restrict__ b_m)
{
  int o = blockIdx.x;
  int t = threadIdx.x;
  __shared__ float wme[256];
  wme[t] = W_m[o * 512 + 256 + t];
  __syncthreads();
  if (t < 224) {
    float s = 0.f;
    if (t < 200) {
      for (int c = 0; c < 256; ++c) s += wme[c] * W_er[c * 200 + t];
    }
    Wcf[o * 224 + t] = s;
  }
  if (t == 0) {
    float s = 0.f;
    for (int c = 0; c < 256; ++c) s += wme[c] * b_er[c];
    cm[o] = s + b_m[o];
  }
}

// Per-edge message + transpose-scatter + per-target aggregation.
__global__ __launch_bounds__(256)
void message_k(const u16* __restrict__ Em, const float* __restrict__ Hm,
               const float* __restrict__ adj, u16* __restrict__ es,
               float* __restrict__ msum)
{
  const int b = blockIdx.y, i = blockIdx.x;
  const int tid = threadIdx.x;
  const int c = tid & 31;
  const int g = tid >> 5;
  __shared__ float red[8][256];
  float accv[8] = {0.f, 0.f, 0.f, 0.f, 0.f, 0.f, 0.f, 0.f};
  const long base_bi = ((long)(b * 128 + i)) * 128;
  for (int w0 = 0; w0 < 128; w0 += 8) {
    const int w = w0 + g;
    const float a = adj[base_bi + w];
    const float s = 1.f / (1.f + __expf(-a));
    const short8 ev = *(const short8*)(Em + (base_bi + w) * 256 + c * 8);
    const float* hp = Hm + ((long)(b * 128 + w)) * 256 + c * 8;
    u16 mb[8];
#pragma unroll
    for (int j = 0; j < 8; ++j) {
      float x = bf2f(((const u16*)&ev)[j]) + hp[j];
      x = fmaxf(x, 0.f) * s;
      accv[j] += x;
      mb[j] = f2bf(x);
    }
    *(short8*)(es + (((long)(b * 128 + w)) * 128 + i) * 256 + c * 8) = *(short8*)mb;
  }
#pragma unroll
  for (int j = 0; j < 8; ++j) red[g][c * 8 + j] = accv[j];
  __syncthreads();
  float s = 0.f;
#pragma unroll
  for (int gg = 0; gg < 8; ++gg) s += red[gg][tid];
  msum[((long)(b * 128 + i)) * 256 + tid] = s;
}

__global__ void gru_k(const float* __restrict__ gi, const float* __restrict__ gh,
                      float* __restrict__ h)
{
  const int n = blockIdx.x;
  const int d = threadIdx.x;
  const int base = n * 768;
  const float r  = 1.f / (1.f + __expf(-(gi[base + d] + gh[base + d])));
  const float z  = 1.f / (1.f + __expf(-(gi[base + 256 + d] + gh[base + 256 + d])));
  const float nn = tanhf(gi[base + 512 + d] + r * gh[base + 512 + d]);
  const int hi = n * 256 + d;
  h[hi] = (1.f - z) * nn + z * h[hi];
}

extern "C" void kernel_launch(void* const* d_in, const int* in_sizes, int n_in,
                              void* d_out, int out_size, void* d_ws, size_t ws_size,
                              hipStream_t stream)
{
  const float* edge = (const float*)d_in[0];
  const float* node = (const float*)d_in[1];
  const float* W_er = (const float*)d_in[2];
  const float* b_er = (const float*)d_in[3];
  const float* W_nr = (const float*)d_in[4];
  const float* b_nr = (const float*)d_in[5];
  const float* Wl1  = (const float*)d_in[6];
  const float* bl1  = (const float*)d_in[7];
  const float* Wl2  = (const float*)d_in[8];
  const float* bl2  = (const float*)d_in[9];
  const float* Wl3  = (const float*)d_in[10];
  const float* bl3  = (const float*)d_in[11];
  const float* W_m  = (const float*)d_in[12];
  const float* b_m  = (const float*)d_in[13];
  const float* W_ih = (const float*)d_in[14];
  const float* b_ih = (const float*)d_in[15];
  const float* W_hh = (const float*)d_in[16];
  const float* b_hh = (const float*)d_in[17];
  const float* W_r  = (const float*)d_in[18];
  const float* b_r  = (const float*)d_in[19];
  (void)in_sizes; (void)n_in; (void)out_size; (void)ws_size;

  float* out_adj = (float*)d_out;            // [8,128,128]
  float* out_lab = (float*)d_out + 131072;   // [8,128,117]

  char* ws = (char*)d_ws;
  size_t off = 0;
  auto alloc = [&](size_t bytes) -> void* {
    void* p = ws + off; off += (bytes + 255) & ~(size_t)255; return p;
  };
  const long E = 131072;
  u16*   es   = (u16*)  alloc(E * 256 * 2);
  u16*   Em   = (u16*)  alloc(E * 256 * 2);
  float* Hm   = (float*)alloc(1024 * 256 * 4);
  float* hbuf = (float*)alloc(1024 * 256 * 4);
  float* msum = (float*)alloc(1024 * 256 * 4);
  float* gi   = (float*)alloc(1024 * 768 * 4);
  float* gh   = (float*)alloc(1024 * 768 * 4);
  u16*   Wcomb = (u16*) alloc(512 * 224 * 2); // [W_er ; W_me@W_er] bf16
  u16*   Wl1b = (u16*)  alloc(512 * 256 * 2);
  u16*   Wl2b = (u16*)  alloc(512 * 512 * 2);
  float* Wcf  = (float*)alloc(256 * 224 * 4);
  float* cmb  = (float*)alloc(256 * 4);
  u16* Wnr_h = (u16*)alloc(256 * 128 * 2); u16* Wnr_l = (u16*)alloc(256 * 128 * 2);
  u16* Wmh_h = (u16*)alloc(256 * 256 * 2); u16* Wmh_l = (u16*)alloc(256 * 256 * 2);
  u16* Wih_h = (u16*)alloc(768 * 256 * 2); u16* Wih_l = (u16*)alloc(768 * 256 * 2);
  u16* Whh_h = (u16*)alloc(768 * 256 * 2); u16* Whh_l = (u16*)alloc(768 * 256 * 2);
  u16* Wr_h  = (u16*)alloc(117 * 256 * 2); u16* Wr_l  = (u16*)alloc(117 * 256 * 2);

  auto cast = [&](u16* dst, const float* src, int rows, int sc, int dc,
                  int stride, int coff) {
    int total = rows * dc;
    cast_pad_k<<<(total + 255) / 256, 256, 0, stream>>>(dst, src, rows, sc, dc,
                                                        stride, coff);
  };
  auto split = [&](u16* dh, u16* dl, const float* src, int rows, int sc, int dc,
                   int stride, int coff) {
    int total = rows * dc;
    cast_split_k<<<(total + 255) / 256, 256, 0, stream>>>(dh, dl, src, rows, sc,
                                                          dc, stride, coff);
  };
  cast(Wcomb, W_er, 256, 200, 224, 200, 0);               // rows 0..255
  wc_k<<<256, 256, 0, stream>>>(Wcf, cmb, W_m, W_er, b_er, b_m);
  cast(Wcomb + 256 * 224, Wcf, 256, 224, 224, 224, 0);    // rows 256..511
  cast(Wl1b, Wl1, 512, 256, 256, 256, 0);
  cast(Wl2b, Wl2, 512, 512, 512, 512, 0);
  split(Wnr_h, Wnr_l, W_nr, 256, 100, 128, 100, 0);
  split(Wmh_h, Wmh_l, W_m, 256, 256, 256, 512, 0);
  split(Wih_h, Wih_l, W_ih, 768, 256, 256, 256, 0);
  split(Whh_h, Whh_l, W_hh, 768, 256, 256, 256, 0);
  split(Wr_h,  Wr_l,  W_r, 117, 256, 256, 256, 0);

  const dim3 blk(256);
  // es (layer-0 e_state) + Em in one pass, edge read once
  fused_front_k<<<2048, blk, 0, stream>>>(edge, Wcomb, b_er, cmb, es, Em);
  // h0 = node @ W_nr^T + b_nr
  gemm_sp_k<false><<<dim3(8, 2), blk, 0, stream>>>(
      node, Wnr_h, Wnr_l, b_nr, hbuf, 256, 128, 100, 100, 256);

  for (int p = 0; p < 3; ++p) {
    // Hm = h @ W_mh^T
    gemm_sp_k<false><<<dim3(8, 2), blk, 0, stream>>>(
        hbuf, Wmh_h, Wmh_l, nullptr, Hm, 256, 256, 256, 256, 256);
    // fused link MLP -> adj (writes out_adj directly, incl. bl3)
    link_k<<<2048, blk, 0, stream>>>(es, Wl1b, bl1, Wl2b, bl2, Wl3, bl3, out_adj);
    // messages, transpose-scatter into e_state, aggregate msum
    message_k<<<dim3(128, 8), blk, 0, stream>>>(Em, Hm, out_adj, es, msum);
    // GRU gates
    gemm_sp_k<false><<<dim3(8, 6), blk, 0, stream>>>(
        msum, Wih_h, Wih_l, b_ih, gi, 768, 256, 256, 256, 768);
    gemm_sp_k<false><<<dim3(8, 6), blk, 0, stream>>>(
        hbuf, Whh_h, Whh_l, b_hh, gh, 768, 256, 256, 256, 768);
    gru_k<<<1024, 256, 0, stream>>>(gi, gh, hbuf);
  }
  // labels = h @ W_r^T + b_r
  gemm_sp_k<false><<<dim3(8, 1), blk, 0, stream>>>(
      hbuf, Wr_h, Wr_l, b_r, out_lab, 117, 256, 256, 256, 117);
}